// Round 7
// baseline (331.368 us; speedup 1.0000x reference)
//
#include <hip/hip_runtime.h>
#include <stdint.h>

#define L_SEQ 2048
#define DMODEL 1024
#define NHEAD 16
#define HDIM 64
#define BATCH 2

typedef __attribute__((ext_vector_type(8))) short bf16x8;
typedef __attribute__((ext_vector_type(4))) float f32x4;

#define MFMA(a, b, c) __builtin_amdgcn_mfma_f32_16x16x32_bf16((a), (b), (c), 0, 0, 0)

#if __has_builtin(__builtin_amdgcn_exp2f)
#define EXP2(x) __builtin_amdgcn_exp2f(x)
#else
#define EXP2(x) exp2f(x)
#endif

// In-wave LDS write->read ordering fence (no inter-wave sync needed: the P
// scratch region is per-wave). Fallback keeps correctness at barrier cost.
#if __has_builtin(__builtin_amdgcn_wave_barrier)
#define WAVE_FENCE() __builtin_amdgcn_wave_barrier()
#else
#define WAVE_FENCE() __syncthreads()
#endif

// log2(e)/32 : folded into Q at the qkv epilogue.
#define QSCALE 0.04508422f

// Round-half-up bf16 (differs from RNE only on exact ties): 2 VALU ops.
__device__ __forceinline__ unsigned short f2bf(float f) {
    return (unsigned short)((__float_as_uint(f) + 0x8000u) >> 16);
}
__device__ __forceinline__ float bf2f(unsigned short h) {
    return __uint_as_float(((unsigned int)h) << 16);
}
// Pack two floats to bf16x2 in 3 VALU ops (2 adds + v_perm).
__device__ __forceinline__ unsigned int pkbf(float a, float b) {
    return __builtin_amdgcn_perm(__float_as_uint(b) + 0x8000u,
                                 __float_as_uint(a) + 0x8000u, 0x07060302u);
}

// Async global->LDS, 16B per lane.
__device__ __forceinline__ void gl2lds16(const unsigned short* g, unsigned short* l) {
    __builtin_amdgcn_global_load_lds(
        (const __attribute__((address_space(1))) void*)g,
        (__attribute__((address_space(3))) void*)l, 16, 0, 0);
}

// ---------------------------------------------------------------------------
// Prep 1: pack mask into uint64 bitmasks.
// ---------------------------------------------------------------------------
__global__ void maskpack_kernel(const int* __restrict__ mask,
                                unsigned long long* __restrict__ mbits) {
    const int w = blockIdx.x;
    const unsigned long long bal = __ballot(mask[w * 64 + threadIdx.x] != 0);
    if (threadIdx.x == 0) mbits[w] = bal;
}

// ---------------------------------------------------------------------------
// Prep 2: split Wo into hi/lo bf16 planes.
// ---------------------------------------------------------------------------
__global__ void wsplit_kernel(const float* __restrict__ W,
                              unsigned short* __restrict__ hi,
                              unsigned short* __restrict__ lo) {
    const int i = (blockIdx.x * 256 + threadIdx.x) * 4;
    const float4 v = *(const float4*)(W + i);
    const float f[4] = {v.x, v.y, v.z, v.w};
    union { unsigned short s[4]; uint2 u; } h, l;
#pragma unroll
    for (int r = 0; r < 4; ++r) {
        h.s[r] = f2bf(f[r]);
        l.s[r] = f2bf(f[r] - bf2f(h.s[r]));
    }
    *(uint2*)&hi[i] = h.u;
    *(uint2*)&lo[i] = l.u;
}

// ---------------------------------------------------------------------------
// Prep 3: RoPE table (cos,sin) per (l,h).
// ---------------------------------------------------------------------------
__global__ void rope_table_kernel(float2* __restrict__ tab) {
    const int idx = blockIdx.x * 256 + threadIdx.x;
    const int l = idx >> 6, h = idx & 63;
    const float invf = powf(10000.0f, -(float)(h & 62) * (1.0f / 64.0f));
    float sn, cs;
    sincosf((float)l * invf, &sn, &cs);
    tab[idx] = make_float2(cs, sn);
}

// ---------------------------------------------------------------------------
// Prep 4: fp32 -> bf16 of q,k,v and Wq,Wk,Wv.
// ---------------------------------------------------------------------------
__global__ void cvt6_kernel(const float* __restrict__ q, const float* __restrict__ k,
                            const float* __restrict__ v, const float* __restrict__ wq,
                            const float* __restrict__ wk, const float* __restrict__ wv,
                            unsigned short* __restrict__ xb, unsigned short* __restrict__ wb) {
    const int t = blockIdx.y;
    const float* src = (t == 0) ? q : (t == 1) ? k : (t == 2) ? v
                     : (t == 3) ? wq : (t == 4) ? wk : wv;
    unsigned short* dst = (t < 3) ? xb + (size_t)t * 4194304
                                  : wb + (size_t)(t - 3) * 1048576;
    const int n = (t < 3) ? 4194304 : 1048576;
    const int i = (blockIdx.x * 256 + threadIdx.x) * 8;
    if (i >= n) return;
    const float4 a = *(const float4*)(src + i);
    const float4 b = *(const float4*)(src + i + 4);
    uint4 u;
    u.x = pkbf(a.x, a.y); u.y = pkbf(a.z, a.w);
    u.z = pkbf(b.x, b.y); u.w = pkbf(b.z, b.w);
    *(uint4*)(dst + i) = u;
}

// ---------------------------------------------------------------------------
// Kernel A: QKV projection (R5 structure; z==0 output scaled by QSCALE so the
// attention kernel's softmax input is already in log2 units).
// ---------------------------------------------------------------------------
__global__ __launch_bounds__(256) void qkv_kernel(
    const unsigned short* __restrict__ Xb, const unsigned short* __restrict__ Wb,
    const float* __restrict__ bq, const float* __restrict__ bk, const float* __restrict__ bv,
    const float2* __restrict__ ropetab,
    unsigned short* __restrict__ Qd, unsigned short* __restrict__ Kd,
    unsigned short* __restrict__ Vd)
{
    const int id = blockIdx.x;
    const int bx = id / 96, rem = id % 96;
    const int z = rem >> 5, by = rem & 31;

    const unsigned short* X = Xb + (size_t)z * (BATCH * L_SEQ * DMODEL);
    const unsigned short* W = Wb + (size_t)z * (DMODEL * DMODEL);
    const float* bias = (z == 0) ? bq : (z == 1) ? bk : bv;

    __shared__ __align__(16) unsigned short As[128 * 64];
    __shared__ __align__(16) unsigned short Bs[128 * 64];

    const int tid  = threadIdx.x;
    const int wave = tid >> 6, lane = tid & 63;
    const int ml = lane & 15, kq = lane >> 4;
    const int m0 = by * 128, n0 = bx * 128;
    const int wm = (wave & 1) * 64, wn = (wave >> 1) * 64;

    f32x4 acc[4][4];
#pragma unroll
    for (int i = 0; i < 4; ++i)
#pragma unroll
        for (int j = 0; j < 4; ++j) acc[i][j] = (f32x4){0.f, 0.f, 0.f, 0.f};

    const int prow = wave * 32 + (lane >> 3);
    const int pch  = (lane & 7) ^ ((lane >> 3) & 7);
    const unsigned short* gA = X + (size_t)(m0 + prow) * DMODEL + pch * 8;
    const unsigned short* gB = W + (size_t)(n0 + prow) * DMODEL + pch * 8;
    unsigned short* lA = As + wave * 2048;
    unsigned short* lB = Bs + wave * 2048;

    for (int kc = 0; kc < DMODEL; kc += 64) {
#pragma unroll
        for (int qq = 0; qq < 4; ++qq) {
            gl2lds16(gA + kc + (size_t)qq * 8 * DMODEL, lA + qq * 512);
            gl2lds16(gB + kc + (size_t)qq * 8 * DMODEL, lB + qq * 512);
        }
        __syncthreads();

        bf16x8 af[2][4], bfv[2][4];
#pragma unroll
        for (int ks = 0; ks < 2; ++ks)
#pragma unroll
            for (int i = 0; i < 4; ++i) {
                const int Ra = wm + i * 16 + ml;
                af[ks][i] = *(const bf16x8*)&As[Ra * 64 + (((ks * 4 + kq) ^ (Ra & 7)) << 3)];
                const int Rb = wn + i * 16 + ml;
                bfv[ks][i] = *(const bf16x8*)&Bs[Rb * 64 + (((ks * 4 + kq) ^ (Rb & 7)) << 3)];
            }
#pragma unroll
        for (int ks = 0; ks < 2; ++ks)
#pragma unroll
            for (int i = 0; i < 4; ++i)
#pragma unroll
                for (int j = 0; j < 4; ++j)
                    acc[i][j] = MFMA(af[ks][i], bfv[ks][j], acc[i][j]);
        __syncthreads();
    }

    if (z < 2) {
        unsigned short* dst = (z == 0) ? Qd : Kd;
        const float osc = (z == 0) ? QSCALE : 1.0f;
#pragma unroll
        for (int jt = 0; jt < 4; ++jt) {
            const int col = n0 + wn + jt * 16 + ml;
            const float bv = bias[col];
            const int nh = col >> 6, hh = col & 63;
            const int odd = hh & 1;
#pragma unroll
            for (int it = 0; it < 4; ++it) {
#pragma unroll
                for (int r = 0; r < 4; ++r) {
                    const int row = m0 + wm + it * 16 + kq * 4 + r;
                    const int bb = row >> 11, ll = row & 2047;
                    const float v = acc[it][jt][r] + bv;
                    const float partner = __shfl_xor(v, 1);
                    const float2 cs = ropetab[ll * 64 + hh];
                    const float res = odd ? fmaf(v, cs.x, partner * cs.y)
                                          : fmaf(v, cs.x, -partner * cs.y);
                    dst[(((size_t)(bb * NHEAD + nh) * L_SEQ + ll) << 6) + hh] = f2bf(res * osc);
                }
            }
        }
    } else {
#pragma unroll
        for (int jt = 0; jt < 4; ++jt) {
            const int col = n0 + wn + jt * 16 + ml;
            const float bv = bias[col];
            const int nh = col >> 6, hh = col & 63;
#pragma unroll
            for (int it = 0; it < 4; ++it) {
                const int rb = m0 + wm + it * 16 + kq * 4;
                const int bb = rb >> 11, ll = rb & 2047;
                uint2 pk;
                pk.x = pkbf(acc[it][jt][0] + bv, acc[it][jt][1] + bv);
                pk.y = pkbf(acc[it][jt][2] + bv, acc[it][jt][3] + bv);
                *(uint2*)&Vd[(((size_t)bb * NHEAD + nh) * HDIM + hh) * L_SEQ + ll] = pk;
            }
        }
    }
}

// ---------------------------------------------------------------------------
// Kernel B: BARRIER-FREE flash attention.
//  - K/V MFMA fragments loaded straight global->VGPR (16B/lane, L1/L2-hit;
//    per-XCD K/V working set 2 MB < 4 MB L2). No K/V LDS staging.
//  - Software pipeline: V(t) and K(t+1) in flight during tile t compute.
//  - Fixed-max softmax in log2 domain (scores pre-scaled in Q): no running
//    max, no alpha rescale, li accumulated per-lane, reduced once at end.
//  - Only LDS: per-wave P C->A layout transform (wave_fence, no syncthreads).
// ---------------------------------------------------------------------------
__global__ __launch_bounds__(256) void attn_kernel(
    const unsigned short* __restrict__ Qr, const unsigned short* __restrict__ Kr,
    const unsigned short* __restrict__ Vt, const unsigned long long* __restrict__ mbits,
    unsigned short* __restrict__ AOhi, unsigned short* __restrict__ AOlo)
{
    __shared__ __align__(16) unsigned short Ps[4 * 32 * 72];  // 18 KB, per-wave regions

    const int tid  = threadIdx.x;
    const int wave = tid >> 6, lane = tid & 63;
    const int ml = lane & 15, kq = lane >> 4;

    const int id = blockIdx.x;
    const int xcd = id & 7, slot = id >> 3;
    const int bh = xcd * 4 + (slot & 3);
    const int qb = slot >> 2;
    const int b = bh >> 4, nh = bh & 15;
    const int q0 = qb * 128;

    const unsigned short* Qp = Qr + (size_t)bh * L_SEQ * HDIM;
    const unsigned short* Kp = Kr + (size_t)bh * L_SEQ * HDIM;
    const unsigned short* Vp = Vt + (size_t)bh * HDIM * L_SEQ;

    const int wq = wave * 32;
    bf16x8 qf[2][2];
#pragma unroll
    for (int qt = 0; qt < 2; ++qt)
#pragma unroll
        for (int c = 0; c < 2; ++c)
            qf[qt][c] = *(const bf16x8*)(Qp + (size_t)(q0 + wq + qt * 16 + ml) * HDIM + c * 32 + kq * 8);

    float li[2] = {0.f, 0.f};
    f32x4 o[2][4];
#pragma unroll
    for (int qt = 0; qt < 2; ++qt)
#pragma unroll
        for (int ht = 0; ht < 4; ++ht) o[qt][ht] = (f32x4){0.f, 0.f, 0.f, 0.f};

    unsigned short* Pw = &Ps[wave * 32 * 72];

    // Fragment base addresses (16B contiguous per lane).
    const unsigned short* kRow = Kp + (size_t)ml * HDIM + kq * 8;          // + (kt*64+nt*16)*64 + c*32
    const unsigned short* vRow = Vp + (size_t)ml * L_SEQ + kq * 8;        // + ht*16*L + kt*64 + c*32

    union U { uint4 u; bf16x8 v; };
    uint4 kbuf[2][8];

    // Preload K tile 0 into kbuf[0].
#pragma unroll
    for (int nt = 0; nt < 4; ++nt) {
        kbuf[0][nt * 2 + 0] = *(const uint4*)(kRow + (size_t)(nt * 16) * HDIM);
        kbuf[0][nt * 2 + 1] = *(const uint4*)(kRow + (size_t)(nt * 16) * HDIM + 32);
    }

    for (int kt2 = 0; kt2 < L_SEQ / 64; kt2 += 2) {
#pragma unroll
        for (int h2 = 0; h2 < 2; ++h2) {
            const int kt = kt2 + h2;

            // V loads for this tile (used after softmax -> latency hidden).
            uint4 vb[8];
#pragma unroll
            for (int ht = 0; ht < 4; ++ht) {
                const unsigned short* va = vRow + (size_t)(ht * 16) * L_SEQ + kt * 64;
                vb[ht * 2 + 0] = *(const uint4*)va;
                vb[ht * 2 + 1] = *(const uint4*)(va + 32);
            }
            // K loads for next tile (clamped re-load on the last iteration).
            const int ktn = (kt + 1 < L_SEQ / 64) ? kt + 1 : kt;
#pragma unroll
            for (int nt = 0; nt < 4; ++nt) {
                const unsigned short* ka = kRow + (size_t)(ktn * 64 + nt * 16) * HDIM;
                kbuf[h2 ^ 1][nt * 2 + 0] = *(const uint4*)ka;
                kbuf[h2 ^ 1][nt * 2 + 1] = *(const uint4*)(ka + 32);
            }

            const unsigned long long mw = mbits[b * 32 + kt];

            // S^T = K·Q^T (scores already in log2 units via Q pre-scale).
            f32x4 st[4][2];
#pragma unroll
            for (int nt = 0; nt < 4; ++nt) {
                U k0, k1;
                k0.u = kbuf[h2][nt * 2 + 0];
                k1.u = kbuf[h2][nt * 2 + 1];
#pragma unroll
                for (int qt = 0; qt < 2; ++qt) {
                    f32x4 c = (f32x4){0.f, 0.f, 0.f, 0.f};
                    c = MFMA(k0.v, qf[qt][0], c);
                    c = MFMA(k1.v, qf[qt][1], c);
                    st[nt][qt] = c;
                }
            }

            // Fixed-max softmax: p = masked ? 0 : exp2(s); li accumulates per-lane.
#pragma unroll
            for (int qt = 0; qt < 2; ++qt) {
#pragma unroll
                for (int nt = 0; nt < 4; ++nt) {
                    const unsigned int nib =
                        ((unsigned int)(mw >> (nt * 16 + kq * 4))) & 0xFu;
                    float p[4];
#pragma unroll
                    for (int r = 0; r < 4; ++r) {
                        const float e = EXP2(st[nt][qt][r]);
                        p[r] = (nib & (1u << r)) ? 0.f : e;
                        li[qt] += p[r];
                    }
                    uint2 pk;
                    pk.x = pkbf(p[0], p[1]);
                    pk.y = pkbf(p[2], p[3]);
                    *(uint2*)&Pw[(qt * 16 + ml) * 72 + nt * 16 + kq * 4] = pk;
                }
            }
            WAVE_FENCE();

            // O^T += V^T·P (no rescale needed with fixed max).
#pragma unroll
            for (int qt = 0; qt < 2; ++qt) {
                const bf16x8 pf0 = *(const bf16x8*)&Pw[(qt * 16 + ml) * 72 + 0 + kq * 8];
                const bf16x8 pf1 = *(const bf16x8*)&Pw[(qt * 16 + ml) * 72 + 32 + kq * 8];
#pragma unroll
                for (int ht = 0; ht < 4; ++ht) {
                    U v0, v1;
                    v0.u = vb[ht * 2 + 0];
                    v1.u = vb[ht * 2 + 1];
                    f32x4 a = o[qt][ht];
                    a = MFMA(v0.v, pf0, a);
                    a = MFMA(v1.v, pf1, a);
                    o[qt][ht] = a;
                }
            }
            WAVE_FENCE();  // Pw reads done before next tile overwrites
        }
    }

    // li: reduce across the 4 kq lane-groups (once, not per tile).
#pragma unroll
    for (int qt = 0; qt < 2; ++qt) {
        li[qt] += __shfl_xor(li[qt], 16);
        li[qt] += __shfl_xor(li[qt], 32);
    }
    const float inv[2] = {1.f / li[0], 1.f / li[1]};

    // Epilogue: per-wave LDS transpose -> coalesced hi/lo plane stores.
    const int qr = lane >> 1, half = lane & 1;
    const size_t gbase = ((size_t)b * L_SEQ + q0 + wq + qr) * DMODEL + nh * 64 + half * 32;

#pragma unroll
    for (int qt = 0; qt < 2; ++qt)
#pragma unroll
        for (int ht = 0; ht < 4; ++ht) {
            uint2 pk;
            pk.x = pkbf(o[qt][ht][0] * inv[qt], o[qt][ht][1] * inv[qt]);
            pk.y = pkbf(o[qt][ht][2] * inv[qt], o[qt][ht][3] * inv[qt]);
            *(uint2*)&Pw[(qt * 16 + ml) * 72 + ht * 16 + kq * 4] = pk;
        }
    WAVE_FENCE();
    {
        const uint4 d0 = *(const uint4*)&Pw[qr * 72 + half * 32];
        const uint4 d1 = *(const uint4*)&Pw[qr * 72 + half * 32 + 8];
        const uint4 d2 = *(const uint4*)&Pw[qr * 72 + half * 32 + 16];
        const uint4 d3 = *(const uint4*)&Pw[qr * 72 + half * 32 + 24];
        *(uint4*)&AOhi[gbase]      = d0;
        *(uint4*)&AOhi[gbase + 8]  = d1;
        *(uint4*)&AOhi[gbase + 16] = d2;
        *(uint4*)&AOhi[gbase + 24] = d3;
    }
    WAVE_FENCE();
#pragma unroll
    for (int qt = 0; qt < 2; ++qt)
#pragma unroll
        for (int ht = 0; ht < 4; ++ht) {
            float lo[4];
#pragma unroll
            for (int r = 0; r < 4; ++r) {
                const float v = o[qt][ht][r] * inv[qt];
                const float hf = __uint_as_float((__float_as_uint(v) + 0x8000u) & 0xffff0000u);
                lo[r] = v - hf;
            }
            uint2 pk;
            pk.x = pkbf(lo[0], lo[1]);
            pk.y = pkbf(lo[2], lo[3]);
            *(uint2*)&Pw[(qt * 16 + ml) * 72 + ht * 16 + kq * 4] = pk;
        }
    WAVE_FENCE();
    {
        const uint4 d0 = *(const uint4*)&Pw[qr * 72 + half * 32];
        const uint4 d1 = *(const uint4*)&Pw[qr * 72 + half * 32 + 8];
        const uint4 d2 = *(const uint4*)&Pw[qr * 72 + half * 32 + 16];
        const uint4 d3 = *(const uint4*)&Pw[qr * 72 + half * 32 + 24];
        *(uint4*)&AOlo[gbase]      = d0;
        *(uint4*)&AOlo[gbase + 8]  = d1;
        *(uint4*)&AOlo[gbase + 16] = d2;
        *(uint4*)&AOlo[gbase + 24] = d3;
    }
}

// ---------------------------------------------------------------------------
// Kernel C: out = AO @ Wo^T + bo (unchanged from R5/R6).
// ---------------------------------------------------------------------------
__global__ __launch_bounds__(256) void oproj_kernel(
    const unsigned short* __restrict__ Ahi_g, const unsigned short* __restrict__ Alo_g,
    const unsigned short* __restrict__ Whi_g, const unsigned short* __restrict__ Wlo_g,
    const float* __restrict__ bias, float* __restrict__ out)
{
    const int id = blockIdx.x;
    const int bx = id >> 5, by = id & 31;

    __shared__ __align__(16) unsigned short Ah[128 * 32], Al[128 * 32];
    __shared__ __align__(16) unsigned short Bh[128 * 32], Bl[128 * 32];

    const int tid  = threadIdx.x;
    const int wave = tid >> 6, lane = tid & 63;
    const int ml = lane & 15, kq = lane >> 4;
    const int m0 = by * 128, n0 = bx * 128;
    const int wm = (wave & 1) * 64, wn = (wave >> 1) * 64;

    f32x4 acc[4][4];
#pragma unroll
    for (int i = 0; i < 4; ++i)
#pragma unroll
        for (int j = 0; j < 4; ++j) acc[i][j] = (f32x4){0.f, 0.f, 0.f, 0.f};

    const int prow = wave * 32 + (lane >> 2);
    const int pch  = (lane & 3) ^ ((lane >> 3) & 3);
    const unsigned short* gAh = Ahi_g + (size_t)(m0 + prow) * DMODEL + pch * 8;
    const unsigned short* gAl = Alo_g + (size_t)(m0 + prow) * DMODEL + pch * 8;
    const unsigned short* gBh = Whi_g + (size_t)(n0 + prow) * DMODEL + pch * 8;
    const unsigned short* gBl = Wlo_g + (size_t)(n0 + prow) * DMODEL + pch * 8;
    unsigned short* lAh = Ah + wave * 1024;
    unsigned short* lAl = Al + wave * 1024;
    unsigned short* lBh = Bh + wave * 1024;
    unsigned short* lBl = Bl + wave * 1024;

    for (int kc = 0; kc < DMODEL; kc += 32) {
#pragma unroll
        for (int qq = 0; qq < 2; ++qq) {
            const size_t go = kc + (size_t)qq * 16 * DMODEL;
            gl2lds16(gAh + go, lAh + qq * 512);
            gl2lds16(gAl + go, lAl + qq * 512);
            gl2lds16(gBh + go, lBh + qq * 512);
            gl2lds16(gBl + go, lBl + qq * 512);
        }
        __syncthreads();

        bf16x8 ah[4], al[4], bh_[4], bl_[4];
#pragma unroll
        for (int i = 0; i < 4; ++i) {
            const int Ra = wm + i * 16 + ml;
            const int sa = Ra * 32 + ((kq ^ ((Ra >> 1) & 3)) << 3);
            ah[i] = *(const bf16x8*)&Ah[sa];
            al[i] = *(const bf16x8*)&Al[sa];
            const int Rb = wn + i * 16 + ml;
            const int sb = Rb * 32 + ((kq ^ ((Rb >> 1) & 3)) << 3);
            bh_[i] = *(const bf16x8*)&Bh[sb];
            bl_[i] = *(const bf16x8*)&Bl[sb];
        }
#pragma unroll
        for (int i = 0; i < 4; ++i)
#pragma unroll
            for (int j = 0; j < 4; ++j) {
                acc[i][j] = MFMA(ah[i], bh_[j], acc[i][j]);
                acc[i][j] = MFMA(al[i], bh_[j], acc[i][j]);
                acc[i][j] = MFMA(ah[i], bl_[j], acc[i][j]);
            }
        __syncthreads();
    }

#pragma unroll
    for (int jt = 0; jt < 4; ++jt) {
        const int col = n0 + wn + jt * 16 + ml;
        const float bv = bias[col];
#pragma unroll
        for (int it = 0; it < 4; ++it)
#pragma unroll
            for (int r = 0; r < 4; ++r) {
                const int row = m0 + wm + it * 16 + kq * 4 + r;
                out[(size_t)row * DMODEL + col] = acc[it][jt][r] + bv;
            }
    }
}

extern "C" void kernel_launch(void* const* d_in, const int* in_sizes, int n_in,
                              void* d_out, int out_size, void* d_ws, size_t ws_size,
                              hipStream_t stream)
{
    (void)in_sizes; (void)n_in; (void)out_size; (void)ws_size;
    const float* q    = (const float*)d_in[0];
    const float* k    = (const float*)d_in[1];
    const float* v    = (const float*)d_in[2];
    const int*   mask = (const int*)d_in[3];
    const float* Wq   = (const float*)d_in[4];
    const float* bq   = (const float*)d_in[5];
    const float* Wk   = (const float*)d_in[6];
    const float* bk   = (const float*)d_in[7];
    const float* Wv   = (const float*)d_in[8];
    const float* bv   = (const float*)d_in[9];
    const float* Wo   = (const float*)d_in[10];
    const float* bo   = (const float*)d_in[11];
    float* out = (float*)d_out;

    const size_t HE = (size_t)BATCH * NHEAD * L_SEQ * HDIM;   // 4,194,304
    const size_t DD = (size_t)DMODEL * DMODEL;                // 1,048,576
    unsigned short* Xb   = (unsigned short*)d_ws;             // 24 MB
    unsigned short* Wb   = Xb + 3 * HE;                       // 6 MB
    unsigned short* Qr   = Wb + 3 * DD;
    unsigned short* Kr   = Qr + HE;
    unsigned short* Vt   = Kr + HE;
    unsigned short* Whi  = Vt + HE;
    unsigned short* Wlo  = Whi + DD;
    unsigned long long* mbits = (unsigned long long*)(Wlo + DD);
    float2* ropetab = (float2*)(mbits + BATCH * L_SEQ / 64);
    unsigned short* AOhi = Xb;          // alias Xb (qkv done reading)
    unsigned short* AOlo = Xb + HE;

    maskpack_kernel<<<dim3(BATCH * L_SEQ / 64), dim3(64), 0, stream>>>(mask, mbits);
    wsplit_kernel<<<dim3(DD / 1024), dim3(256), 0, stream>>>(Wo, Whi, Wlo);
    rope_table_kernel<<<dim3(L_SEQ * HDIM / 256), dim3(256), 0, stream>>>(ropetab);
    cvt6_kernel<<<dim3(2048, 6), dim3(256), 0, stream>>>(q, k, v, Wq, Wk, Wv, Xb, Wb);

    qkv_kernel<<<dim3(768), dim3(256), 0, stream>>>(Xb, Wb, bq, bk, bv, ropetab, Qr, Kr, Vt);

    attn_kernel<<<dim3(512), dim3(256), 0, stream>>>(Qr, Kr, Vt, mbits, AOhi, AOlo);

    oproj_kernel<<<dim3(256), dim3(256), 0, stream>>>(AOhi, AOlo, Whi, Wlo, bo, out);
}

// Round 8
// 267.478 us; speedup vs baseline: 1.2389x; 1.2389x over previous
//
#include <hip/hip_runtime.h>
#include <stdint.h>

#define L_SEQ 2048
#define DMODEL 1024
#define NHEAD 16
#define HDIM 64
#define BATCH 2

typedef __attribute__((ext_vector_type(8))) short bf16x8;
typedef __attribute__((ext_vector_type(4))) float f32x4;

#define MFMA(a, b, c) __builtin_amdgcn_mfma_f32_16x16x32_bf16((a), (b), (c), 0, 0, 0)

#if __has_builtin(__builtin_amdgcn_exp2f)
#define EXP2(x) __builtin_amdgcn_exp2f(x)
#else
#define EXP2(x) exp2f(x)
#endif

#if __has_builtin(__builtin_amdgcn_wave_barrier)
#define WAVE_FENCE() __builtin_amdgcn_wave_barrier()
#else
#define WAVE_FENCE() __syncthreads()
#endif

// log2(e)/32 : folded into Q at the qkv epilogue (fixed-max softmax).
#define QSCALE 0.04508422f

__device__ __forceinline__ unsigned short f2bf(float f) {
    return (unsigned short)((__float_as_uint(f) + 0x8000u) >> 16);
}
__device__ __forceinline__ float bf2f(unsigned short h) {
    return __uint_as_float(((unsigned int)h) << 16);
}
__device__ __forceinline__ unsigned int pkbf(float a, float b) {
    return __builtin_amdgcn_perm(__float_as_uint(b) + 0x8000u,
                                 __float_as_uint(a) + 0x8000u, 0x07060302u);
}
__device__ __forceinline__ void gl2lds16(const unsigned short* g, unsigned short* l) {
    __builtin_amdgcn_global_load_lds(
        (const __attribute__((address_space(1))) void*)g,
        (__attribute__((address_space(3))) void*)l, 16, 0, 0);
}

// ---------------------------------------------------------------------------
// Merged prep kernel (one launch instead of four):
//  y<6 : fp32->bf16 convert of q,k,v (4M each) / Wq,Wk,Wv (1M each)
//  y==6: Wo hi/lo bf16 split
//  y==7: x<512 RoPE table; 512<=x<528 mask bit-pack
// ---------------------------------------------------------------------------
__global__ void prep_kernel(
    const float* __restrict__ q, const float* __restrict__ k, const float* __restrict__ v,
    const float* __restrict__ wq, const float* __restrict__ wk, const float* __restrict__ wv,
    const float* __restrict__ Wo, const int* __restrict__ mask,
    unsigned short* __restrict__ xb, unsigned short* __restrict__ wb,
    unsigned short* __restrict__ whi, unsigned short* __restrict__ wlo,
    float2* __restrict__ ropetab, unsigned long long* __restrict__ mbits)
{
    const int y = blockIdx.y, x = blockIdx.x, tid = threadIdx.x;
    if (y < 6) {
        const float* src = (y == 0) ? q : (y == 1) ? k : (y == 2) ? v
                         : (y == 3) ? wq : (y == 4) ? wk : wv;
        unsigned short* dst = (y < 3) ? xb + (size_t)y * 4194304
                                      : wb + (size_t)(y - 3) * 1048576;
        const int n = (y < 3) ? 4194304 : 1048576;
        const int i = (x * 256 + tid) * 8;
        if (i >= n) return;
        const float4 a = *(const float4*)(src + i);
        const float4 b = *(const float4*)(src + i + 4);
        uint4 u;
        u.x = pkbf(a.x, a.y); u.y = pkbf(a.z, a.w);
        u.z = pkbf(b.x, b.y); u.w = pkbf(b.z, b.w);
        *(uint4*)(dst + i) = u;
    } else if (y == 6) {
        const int i = (x * 256 + tid) * 4;
        if (i >= DMODEL * DMODEL) return;
        const float4 vv = *(const float4*)(Wo + i);
        const float f[4] = {vv.x, vv.y, vv.z, vv.w};
        union { unsigned short s[4]; uint2 u; } h, l;
#pragma unroll
        for (int r = 0; r < 4; ++r) {
            h.s[r] = f2bf(f[r]);
            l.s[r] = f2bf(f[r] - bf2f(h.s[r]));
        }
        *(uint2*)&whi[i] = h.u;
        *(uint2*)&wlo[i] = l.u;
    } else {
        if (x < 512) {
            const int idx = x * 256 + tid;
            const int l = idx >> 6, h = idx & 63;
            const float invf = powf(10000.0f, -(float)(h & 62) * (1.0f / 64.0f));
            float sn, cs;
            sincosf((float)l * invf, &sn, &cs);
            ropetab[idx] = make_float2(cs, sn);
        } else if (x < 528) {
            const int w = (x - 512) * 4 + (tid >> 6);
            const unsigned long long bal = __ballot(mask[w * 64 + (tid & 63)] != 0);
            if ((tid & 63) == 0) mbits[w] = bal;
        }
    }
}

// ---------------------------------------------------------------------------
// Kernel A: QKV projection (R5 structure; Q scaled by QSCALE).
// ---------------------------------------------------------------------------
__global__ __launch_bounds__(256) void qkv_kernel(
    const unsigned short* __restrict__ Xb, const unsigned short* __restrict__ Wb,
    const float* __restrict__ bq, const float* __restrict__ bk, const float* __restrict__ bv,
    const float2* __restrict__ ropetab,
    unsigned short* __restrict__ Qd, unsigned short* __restrict__ Kd,
    unsigned short* __restrict__ Vd)
{
    const int id = blockIdx.x;
    const int bx = id / 96, rem = id % 96;
    const int z = rem >> 5, by = rem & 31;

    const unsigned short* X = Xb + (size_t)z * (BATCH * L_SEQ * DMODEL);
    const unsigned short* W = Wb + (size_t)z * (DMODEL * DMODEL);
    const float* bias = (z == 0) ? bq : (z == 1) ? bk : bv;

    __shared__ __align__(16) unsigned short As[128 * 64];
    __shared__ __align__(16) unsigned short Bs[128 * 64];

    const int tid  = threadIdx.x;
    const int wave = tid >> 6, lane = tid & 63;
    const int ml = lane & 15, kq = lane >> 4;
    const int m0 = by * 128, n0 = bx * 128;
    const int wm = (wave & 1) * 64, wn = (wave >> 1) * 64;

    f32x4 acc[4][4];
#pragma unroll
    for (int i = 0; i < 4; ++i)
#pragma unroll
        for (int j = 0; j < 4; ++j) acc[i][j] = (f32x4){0.f, 0.f, 0.f, 0.f};

    const int prow = wave * 32 + (lane >> 3);
    const int pch  = (lane & 7) ^ ((lane >> 3) & 7);
    const unsigned short* gA = X + (size_t)(m0 + prow) * DMODEL + pch * 8;
    const unsigned short* gB = W + (size_t)(n0 + prow) * DMODEL + pch * 8;
    unsigned short* lA = As + wave * 2048;
    unsigned short* lB = Bs + wave * 2048;

    for (int kc = 0; kc < DMODEL; kc += 64) {
#pragma unroll
        for (int qq = 0; qq < 4; ++qq) {
            gl2lds16(gA + kc + (size_t)qq * 8 * DMODEL, lA + qq * 512);
            gl2lds16(gB + kc + (size_t)qq * 8 * DMODEL, lB + qq * 512);
        }
        __syncthreads();

        bf16x8 af[2][4], bfv[2][4];
#pragma unroll
        for (int ks = 0; ks < 2; ++ks)
#pragma unroll
            for (int i = 0; i < 4; ++i) {
                const int Ra = wm + i * 16 + ml;
                af[ks][i] = *(const bf16x8*)&As[Ra * 64 + (((ks * 4 + kq) ^ (Ra & 7)) << 3)];
                const int Rb = wn + i * 16 + ml;
                bfv[ks][i] = *(const bf16x8*)&Bs[Rb * 64 + (((ks * 4 + kq) ^ (Rb & 7)) << 3)];
            }
#pragma unroll
        for (int ks = 0; ks < 2; ++ks)
#pragma unroll
            for (int i = 0; i < 4; ++i)
#pragma unroll
                for (int j = 0; j < 4; ++j)
                    acc[i][j] = MFMA(af[ks][i], bfv[ks][j], acc[i][j]);
        __syncthreads();
    }

    if (z < 2) {
        unsigned short* dst = (z == 0) ? Qd : Kd;
        const float osc = (z == 0) ? QSCALE : 1.0f;
#pragma unroll
        for (int jt = 0; jt < 4; ++jt) {
            const int col = n0 + wn + jt * 16 + ml;
            const float bv = bias[col];
            const int nh = col >> 6, hh = col & 63;
            const int odd = hh & 1;
#pragma unroll
            for (int it = 0; it < 4; ++it) {
#pragma unroll
                for (int r = 0; r < 4; ++r) {
                    const int row = m0 + wm + it * 16 + kq * 4 + r;
                    const int bb = row >> 11, ll = row & 2047;
                    const float v = acc[it][jt][r] + bv;
                    const float partner = __shfl_xor(v, 1);
                    const float2 cs = ropetab[ll * 64 + hh];
                    const float res = odd ? fmaf(v, cs.x, partner * cs.y)
                                          : fmaf(v, cs.x, -partner * cs.y);
                    dst[(((size_t)(bb * NHEAD + nh) * L_SEQ + ll) << 6) + hh] = f2bf(res * osc);
                }
            }
        }
    } else {
#pragma unroll
        for (int jt = 0; jt < 4; ++jt) {
            const int col = n0 + wn + jt * 16 + ml;
            const float bv = bias[col];
            const int nh = col >> 6, hh = col & 63;
#pragma unroll
            for (int it = 0; it < 4; ++it) {
                const int rb = m0 + wm + it * 16 + kq * 4;
                const int bb = rb >> 11, ll = rb & 2047;
                uint2 pk;
                pk.x = pkbf(acc[it][jt][0] + bv, acc[it][jt][1] + bv);
                pk.y = pkbf(acc[it][jt][2] + bv, acc[it][jt][3] + bv);
                *(uint2*)&Vd[(((size_t)bb * NHEAD + nh) * HDIM + hh) * L_SEQ + ll] = pk;
            }
        }
    }
}

// ---------------------------------------------------------------------------
// Kernel B: flash attention, LDS-staged + double-buffered global_load_lds,
// ONE barrier per tile (loads for t+1 issued after the barrier, in flight
// during tile-t compute). Fixed-max log2 softmax (Q pre-scaled). 64 q/block
// (16 q/wave), 1024 blocks = 4 blocks/CU, LDS exactly 40 KB.
// ---------------------------------------------------------------------------
__global__ __launch_bounds__(256) void attn_kernel(
    const unsigned short* __restrict__ Qr, const unsigned short* __restrict__ Kr,
    const unsigned short* __restrict__ Vt, const unsigned long long* __restrict__ mbits,
    unsigned short* __restrict__ AOhi, unsigned short* __restrict__ AOlo)
{
    __shared__ __align__(16) unsigned short Ks[2][64 * 64];  // 16 KB
    __shared__ __align__(16) unsigned short Vs[2][64 * 64];  // 16 KB
    __shared__ __align__(16) unsigned short Ps[4][16 * 64];  // 8 KB (per-wave)

    const int tid  = threadIdx.x;
    const int wave = tid >> 6, lane = tid & 63;
    const int ml = lane & 15, kq = lane >> 4;

    // 1024 blocks: xcd-major so 4 bh share an XCD's L2.
    const int id = blockIdx.x;
    const int xcd = id & 7, slot = id >> 3;       // slot 0..127
    const int bh = xcd * 4 + (slot & 3);
    const int qb = slot >> 2;                     // 0..31
    const int b = bh >> 4, nh = bh & 15;
    const int q0 = qb * 64;
    const int wq = wave * 16;

    const unsigned short* Qp = Qr + (size_t)bh * L_SEQ * HDIM;
    const unsigned short* Kp = Kr + (size_t)bh * L_SEQ * HDIM;
    const unsigned short* Vp = Vt + (size_t)bh * HDIM * L_SEQ;

    // Q fragments: 16 q rows per wave (q = ml), two 32-wide k-chunks.
    bf16x8 qf0 = *(const bf16x8*)(Qp + (size_t)(q0 + wq + ml) * HDIM + kq * 8);
    bf16x8 qf1 = *(const bf16x8*)(Qp + (size_t)(q0 + wq + ml) * HDIM + 32 + kq * 8);

    float li = 0.f;
    f32x4 o[4];
#pragma unroll
    for (int ht = 0; ht < 4; ++ht) o[ht] = (f32x4){0.f, 0.f, 0.f, 0.f};

    unsigned short* Pw = Ps[wave];

    // Staging geometry: wave stages rows [wave*16, +16) in 2 issues of 8 rows.
    // Lane l -> row +l>>3, phys chunk l&7 holds logical (l&7)^(l>>3).
    const int srow8 = lane >> 3;
    const int sch   = (lane & 7) ^ srow8;
    const unsigned short* gK = Kp + (size_t)(wave * 16 + srow8) * HDIM + sch * 8;
    const unsigned short* gV = Vp + (size_t)(wave * 16 + srow8) * L_SEQ + sch * 8;

#define STAGE(kt, bf)                                                          \
    do {                                                                       \
        gl2lds16(gK + (size_t)((kt) * 64) * HDIM, &Ks[bf][(wave * 16) * 64]);  \
        gl2lds16(gK + (size_t)((kt) * 64 + 8) * HDIM,                          \
                 &Ks[bf][(wave * 16 + 8) * 64]);                               \
        gl2lds16(gV + (kt) * 64, &Vs[bf][(wave * 16) * 64]);                   \
        gl2lds16(gV + (size_t)8 * L_SEQ + (kt) * 64,                           \
                 &Vs[bf][(wave * 16 + 8) * 64]);                               \
    } while (0)

    STAGE(0, 0);

    for (int kt = 0; kt < L_SEQ / 64; ++kt) {
        const int buf = kt & 1;
        __syncthreads();                       // tile kt staged (vmcnt drain)
        if (kt + 1 < L_SEQ / 64) STAGE(kt + 1, buf ^ 1);  // fly during compute

        const unsigned short* Kb = Ks[buf];
        const unsigned short* Vb = Vs[buf];
        const unsigned long long mw = mbits[b * 32 + kt];

        // S^T = K·Q^T : lane holds keys nt*16+kq*4+r for q=ml.
        f32x4 st[4];
#pragma unroll
        for (int nt = 0; nt < 4; ++nt) {
            const int R = nt * 16 + ml;
            const bf16x8 kf0 = *(const bf16x8*)&Kb[R * 64 + ((kq ^ (R & 7)) << 3)];
            const bf16x8 kf1 = *(const bf16x8*)&Kb[R * 64 + (((4 + kq) ^ (R & 7)) << 3)];
            f32x4 c = (f32x4){0.f, 0.f, 0.f, 0.f};
            c = MFMA(kf0, qf0, c);
            c = MFMA(kf1, qf1, c);
            st[nt] = c;
        }

        // Fixed-max softmax; P -> per-wave LDS (swizzled, unpadded).
#pragma unroll
        for (int nt = 0; nt < 4; ++nt) {
            const unsigned int nib = ((unsigned int)(mw >> (nt * 16 + kq * 4))) & 0xFu;
            float p[4];
#pragma unroll
            for (int r = 0; r < 4; ++r) {
                const float e = EXP2(st[nt][r]);
                p[r] = (nib & (1u << r)) ? 0.f : e;
                li += p[r];
            }
            uint2 pk;
            pk.x = pkbf(p[0], p[1]);
            pk.y = pkbf(p[2], p[3]);
            const int ck = nt * 2 + (kq >> 1);
            *(uint2*)&Pw[ml * 64 + ((ck ^ (ml & 7)) << 3) + (kq & 1) * 4] = pk;
        }
        WAVE_FENCE();

        // O^T += V^T·P
        const bf16x8 pf0 = *(const bf16x8*)&Pw[ml * 64 + ((kq ^ (ml & 7)) << 3)];
        const bf16x8 pf1 = *(const bf16x8*)&Pw[ml * 64 + (((4 + kq) ^ (ml & 7)) << 3)];
#pragma unroll
        for (int ht = 0; ht < 4; ++ht) {
            const int R = ht * 16 + ml;
            const bf16x8 vf0 = *(const bf16x8*)&Vb[R * 64 + ((kq ^ (R & 7)) << 3)];
            const bf16x8 vf1 = *(const bf16x8*)&Vb[R * 64 + (((4 + kq) ^ (R & 7)) << 3)];
            o[ht] = MFMA(vf0, pf0, o[ht]);
            o[ht] = MFMA(vf1, pf1, o[ht]);
        }
        WAVE_FENCE();  // Pw reads done before next tile overwrites
    }
#undef STAGE

    // li spans lanes ml, ml+16, ml+32, ml+48.
    li += __shfl_xor(li, 16);
    li += __shfl_xor(li, 32);
    const float inv = 1.f / li;

    // Epilogue: O^T lane holds (h=ht*16+kq*4+r, q=ml). Transpose via Pw.
    const int qr = lane >> 2, quarter = lane & 3;
    const size_t gbase = ((size_t)b * L_SEQ + q0 + wq + qr) * DMODEL + nh * 64 + quarter * 16;
    const int rc0 = (quarter * 2) ^ (qr & 7), rc1 = (quarter * 2 + 1) ^ (qr & 7);

#pragma unroll
    for (int ht = 0; ht < 4; ++ht) {
        uint2 pk;
        pk.x = pkbf(o[ht][0] * inv, o[ht][1] * inv);
        pk.y = pkbf(o[ht][2] * inv, o[ht][3] * inv);
        const int ck = ht * 2 + (kq >> 1);
        *(uint2*)&Pw[ml * 64 + ((ck ^ (ml & 7)) << 3) + (kq & 1) * 4] = pk;
    }
    WAVE_FENCE();
    {
        const uint4 d0 = *(const uint4*)&Pw[qr * 64 + (rc0 << 3)];
        const uint4 d1 = *(const uint4*)&Pw[qr * 64 + (rc1 << 3)];
        *(uint4*)&AOhi[gbase]     = d0;
        *(uint4*)&AOhi[gbase + 8] = d1;
    }
    WAVE_FENCE();
#pragma unroll
    for (int ht = 0; ht < 4; ++ht) {
        float lo[4];
#pragma unroll
        for (int r = 0; r < 4; ++r) {
            const float v = o[ht][r] * inv;
            const float hf = __uint_as_float((__float_as_uint(v) + 0x8000u) & 0xffff0000u);
            lo[r] = v - hf;
        }
        uint2 pk;
        pk.x = pkbf(lo[0], lo[1]);
        pk.y = pkbf(lo[2], lo[3]);
        const int ck = ht * 2 + (kq >> 1);
        *(uint2*)&Pw[ml * 64 + ((ck ^ (ml & 7)) << 3) + (kq & 1) * 4] = pk;
    }
    WAVE_FENCE();
    {
        const uint4 d0 = *(const uint4*)&Pw[qr * 64 + (rc0 << 3)];
        const uint4 d1 = *(const uint4*)&Pw[qr * 64 + (rc1 << 3)];
        *(uint4*)&AOlo[gbase]     = d0;
        *(uint4*)&AOlo[gbase + 8] = d1;
    }
}

// ---------------------------------------------------------------------------
// Kernel C: out = AO @ Wo^T + bo (unchanged).
// ---------------------------------------------------------------------------
__global__ __launch_bounds__(256) void oproj_kernel(
    const unsigned short* __restrict__ Ahi_g, const unsigned short* __restrict__ Alo_g,
    const unsigned short* __restrict__ Whi_g, const unsigned short* __restrict__ Wlo_g,
    const float* __restrict__ bias, float* __restrict__ out)
{
    const int id = blockIdx.x;
    const int bx = id >> 5, by = id & 31;

    __shared__ __align__(16) unsigned short Ah[128 * 32], Al[128 * 32];
    __shared__ __align__(16) unsigned short Bh[128 * 32], Bl[128 * 32];

    const int tid  = threadIdx.x;
    const int wave = tid >> 6, lane = tid & 63;
    const int ml = lane & 15, kq = lane >> 4;
    const int m0 = by * 128, n0 = bx * 128;
    const int wm = (wave & 1) * 64, wn = (wave >> 1) * 64;

    f32x4 acc[4][4];
#pragma unroll
    for (int i = 0; i < 4; ++i)
#pragma unroll
        for (int j = 0; j < 4; ++j) acc[i][j] = (f32x4){0.f, 0.f, 0.f, 0.f};

    const int prow = wave * 32 + (lane >> 2);
    const int pch  = (lane & 3) ^ ((lane >> 3) & 3);
    const unsigned short* gAh = Ahi_g + (size_t)(m0 + prow) * DMODEL + pch * 8;
    const unsigned short* gAl = Alo_g + (size_t)(m0 + prow) * DMODEL + pch * 8;
    const unsigned short* gBh = Whi_g + (size_t)(n0 + prow) * DMODEL + pch * 8;
    const unsigned short* gBl = Wlo_g + (size_t)(n0 + prow) * DMODEL + pch * 8;
    unsigned short* lAh = Ah + wave * 1024;
    unsigned short* lAl = Al + wave * 1024;
    unsigned short* lBh = Bh + wave * 1024;
    unsigned short* lBl = Bl + wave * 1024;

    for (int kc = 0; kc < DMODEL; kc += 32) {
#pragma unroll
        for (int qq = 0; qq < 2; ++qq) {
            const size_t go = kc + (size_t)qq * 16 * DMODEL;
            gl2lds16(gAh + go, lAh + qq * 512);
            gl2lds16(gAl + go, lAl + qq * 512);
            gl2lds16(gBh + go, lBh + qq * 512);
            gl2lds16(gBl + go, lBl + qq * 512);
        }
        __syncthreads();

        bf16x8 ah[4], al[4], bh_[4], bl_[4];
#pragma unroll
        for (int i = 0; i < 4; ++i) {
            const int Ra = wm + i * 16 + ml;
            const int sa = Ra * 32 + ((kq ^ ((Ra >> 1) & 3)) << 3);
            ah[i] = *(const bf16x8*)&Ah[sa];
            al[i] = *(const bf16x8*)&Al[sa];
            const int Rb = wn + i * 16 + ml;
            const int sb = Rb * 32 + ((kq ^ ((Rb >> 1) & 3)) << 3);
            bh_[i] = *(const bf16x8*)&Bh[sb];
            bl_[i] = *(const bf16x8*)&Bl[sb];
        }
#pragma unroll
        for (int i = 0; i < 4; ++i)
#pragma unroll
            for (int j = 0; j < 4; ++j) {
                acc[i][j] = MFMA(ah[i], bh_[j], acc[i][j]);
                acc[i][j] = MFMA(al[i], bh_[j], acc[i][j]);
                acc[i][j] = MFMA(ah[i], bl_[j], acc[i][j]);
            }
        __syncthreads();
    }

#pragma unroll
    for (int jt = 0; jt < 4; ++jt) {
        const int col = n0 + wn + jt * 16 + ml;
        const float bv = bias[col];
#pragma unroll
        for (int it = 0; it < 4; ++it)
#pragma unroll
            for (int r = 0; r < 4; ++r) {
                const int row = m0 + wm + it * 16 + kq * 4 + r;
                out[(size_t)row * DMODEL + col] = acc[it][jt][r] + bv;
            }
    }
}

extern "C" void kernel_launch(void* const* d_in, const int* in_sizes, int n_in,
                              void* d_out, int out_size, void* d_ws, size_t ws_size,
                              hipStream_t stream)
{
    (void)in_sizes; (void)n_in; (void)out_size; (void)ws_size;
    const float* q    = (const float*)d_in[0];
    const float* k    = (const float*)d_in[1];
    const float* v    = (const float*)d_in[2];
    const int*   mask = (const int*)d_in[3];
    const float* Wq   = (const float*)d_in[4];
    const float* bq   = (const float*)d_in[5];
    const float* Wk   = (const float*)d_in[6];
    const float* bk   = (const float*)d_in[7];
    const float* Wv   = (const float*)d_in[8];
    const float* bv   = (const float*)d_in[9];
    const float* Wo   = (const float*)d_in[10];
    const float* bo   = (const float*)d_in[11];
    float* out = (float*)d_out;

    const size_t HE = (size_t)BATCH * NHEAD * L_SEQ * HDIM;   // 4,194,304
    const size_t DD = (size_t)DMODEL * DMODEL;                // 1,048,576
    unsigned short* Xb   = (unsigned short*)d_ws;             // 24 MB
    unsigned short* Wb   = Xb + 3 * HE;                       // 6 MB
    unsigned short* Qr   = Wb + 3 * DD;
    unsigned short* Kr   = Qr + HE;
    unsigned short* Vt   = Kr + HE;
    unsigned short* Whi  = Vt + HE;
    unsigned short* Wlo  = Whi + DD;
    unsigned long long* mbits = (unsigned long long*)(Wlo + DD);
    float2* ropetab = (float2*)(mbits + BATCH * L_SEQ / 64);
    unsigned short* AOhi = Xb;          // alias Xb (qkv done reading)
    unsigned short* AOlo = Xb + HE;

    prep_kernel<<<dim3(2048, 8), dim3(256), 0, stream>>>(
        q, k, v, Wq, Wk, Wv, Wo, mask, Xb, Wb, Whi, Wlo, ropetab, mbits);

    qkv_kernel<<<dim3(768), dim3(256), 0, stream>>>(Xb, Wb, bq, bk, bv, ropetab, Qr, Kr, Vt);

    attn_kernel<<<dim3(1024), dim3(256), 0, stream>>>(Qr, Kr, Vt, mbits, AOhi, AOlo);

    oproj_kernel<<<dim3(256), dim3(256), 0, stream>>>(AOhi, AOlo, Whi, Wlo, bo, out);
}

// Round 9
// 257.326 us; speedup vs baseline: 1.2877x; 1.0395x over previous
//
#include <hip/hip_runtime.h>
#include <stdint.h>

#define L_SEQ 2048
#define DMODEL 1024
#define NHEAD 16
#define HDIM 64
#define BATCH 2

typedef __attribute__((ext_vector_type(8))) short bf16x8;
typedef __attribute__((ext_vector_type(4))) float f32x4;

#define MFMA(a, b, c) __builtin_amdgcn_mfma_f32_16x16x32_bf16((a), (b), (c), 0, 0, 0)

#if __has_builtin(__builtin_amdgcn_exp2f)
#define EXP2(x) __builtin_amdgcn_exp2f(x)
#else
#define EXP2(x) exp2f(x)
#endif

#if __has_builtin(__builtin_amdgcn_wave_barrier)
#define WAVE_FENCE() __builtin_amdgcn_wave_barrier()
#else
#define WAVE_FENCE() __syncthreads()
#endif

// log2(e)/32 : folded into Q at the qkv epilogue (fixed-max softmax).
#define QSCALE 0.04508422f

__device__ __forceinline__ unsigned short f2bf(float f) {
    return (unsigned short)((__float_as_uint(f) + 0x8000u) >> 16);
}
__device__ __forceinline__ float bf2f(unsigned short h) {
    return __uint_as_float(((unsigned int)h) << 16);
}
__device__ __forceinline__ unsigned int pkbf(float a, float b) {
    return __builtin_amdgcn_perm(__float_as_uint(b) + 0x8000u,
                                 __float_as_uint(a) + 0x8000u, 0x07060302u);
}
__device__ __forceinline__ void gl2lds16(const unsigned short* g, unsigned short* l) {
    __builtin_amdgcn_global_load_lds(
        (const __attribute__((address_space(1))) void*)g,
        (__attribute__((address_space(3))) void*)l, 16, 0, 0);
}

// ---------------------------------------------------------------------------
// Merged prep kernel:
//  y<6 : fp32->bf16 convert of q,k,v / Wq,Wk,Wv
//  y==6: Wo hi/lo bf16 split
//  y==7: x<512 RoPE table; 512<=x<528 mask bit-pack
// ---------------------------------------------------------------------------
__global__ void prep_kernel(
    const float* __restrict__ q, const float* __restrict__ k, const float* __restrict__ v,
    const float* __restrict__ wq, const float* __restrict__ wk, const float* __restrict__ wv,
    const float* __restrict__ Wo, const int* __restrict__ mask,
    unsigned short* __restrict__ xb, unsigned short* __restrict__ wb,
    unsigned short* __restrict__ whi, unsigned short* __restrict__ wlo,
    float2* __restrict__ ropetab, unsigned long long* __restrict__ mbits)
{
    const int y = blockIdx.y, x = blockIdx.x, tid = threadIdx.x;
    if (y < 6) {
        const float* src = (y == 0) ? q : (y == 1) ? k : (y == 2) ? v
                         : (y == 3) ? wq : (y == 4) ? wk : wv;
        unsigned short* dst = (y < 3) ? xb + (size_t)y * 4194304
                                      : wb + (size_t)(y - 3) * 1048576;
        const int n = (y < 3) ? 4194304 : 1048576;
        const int i = (x * 256 + tid) * 8;
        if (i >= n) return;
        const float4 a = *(const float4*)(src + i);
        const float4 b = *(const float4*)(src + i + 4);
        uint4 u;
        u.x = pkbf(a.x, a.y); u.y = pkbf(a.z, a.w);
        u.z = pkbf(b.x, b.y); u.w = pkbf(b.z, b.w);
        *(uint4*)(dst + i) = u;
    } else if (y == 6) {
        const int i = (x * 256 + tid) * 4;
        if (i >= DMODEL * DMODEL) return;
        const float4 vv = *(const float4*)(Wo + i);
        const float f[4] = {vv.x, vv.y, vv.z, vv.w};
        union { unsigned short s[4]; uint2 u; } h, l;
#pragma unroll
        for (int r = 0; r < 4; ++r) {
            h.s[r] = f2bf(f[r]);
            l.s[r] = f2bf(f[r] - bf2f(h.s[r]));
        }
        *(uint2*)&whi[i] = h.u;
        *(uint2*)&wlo[i] = l.u;
    } else {
        if (x < 512) {
            const int idx = x * 256 + tid;
            const int l = idx >> 6, h = idx & 63;
            const float invf = powf(10000.0f, -(float)(h & 62) * (1.0f / 64.0f));
            float sn, cs;
            sincosf((float)l * invf, &sn, &cs);
            ropetab[idx] = make_float2(cs, sn);
        } else if (x < 528) {
            const int w = (x - 512) * 4 + (tid >> 6);
            const unsigned long long bal = __ballot(mask[w * 64 + (tid & 63)] != 0);
            if ((tid & 63) == 0) mbits[w] = bal;
        }
    }
}

// ---------------------------------------------------------------------------
// Kernel A: QKV projection (unchanged from R8; Q scaled by QSCALE).
// ---------------------------------------------------------------------------
__global__ __launch_bounds__(256) void qkv_kernel(
    const unsigned short* __restrict__ Xb, const unsigned short* __restrict__ Wb,
    const float* __restrict__ bq, const float* __restrict__ bk, const float* __restrict__ bv,
    const float2* __restrict__ ropetab,
    unsigned short* __restrict__ Qd, unsigned short* __restrict__ Kd,
    unsigned short* __restrict__ Vd)
{
    const int id = blockIdx.x;
    const int bx = id / 96, rem = id % 96;
    const int z = rem >> 5, by = rem & 31;

    const unsigned short* X = Xb + (size_t)z * (BATCH * L_SEQ * DMODEL);
    const unsigned short* W = Wb + (size_t)z * (DMODEL * DMODEL);
    const float* bias = (z == 0) ? bq : (z == 1) ? bk : bv;

    __shared__ __align__(16) unsigned short As[128 * 64];
    __shared__ __align__(16) unsigned short Bs[128 * 64];

    const int tid  = threadIdx.x;
    const int wave = tid >> 6, lane = tid & 63;
    const int ml = lane & 15, kq = lane >> 4;
    const int m0 = by * 128, n0 = bx * 128;
    const int wm = (wave & 1) * 64, wn = (wave >> 1) * 64;

    f32x4 acc[4][4];
#pragma unroll
    for (int i = 0; i < 4; ++i)
#pragma unroll
        for (int j = 0; j < 4; ++j) acc[i][j] = (f32x4){0.f, 0.f, 0.f, 0.f};

    const int prow = wave * 32 + (lane >> 3);
    const int pch  = (lane & 7) ^ ((lane >> 3) & 7);
    const unsigned short* gA = X + (size_t)(m0 + prow) * DMODEL + pch * 8;
    const unsigned short* gB = W + (size_t)(n0 + prow) * DMODEL + pch * 8;
    unsigned short* lA = As + wave * 2048;
    unsigned short* lB = Bs + wave * 2048;

    for (int kc = 0; kc < DMODEL; kc += 64) {
#pragma unroll
        for (int qq = 0; qq < 4; ++qq) {
            gl2lds16(gA + kc + (size_t)qq * 8 * DMODEL, lA + qq * 512);
            gl2lds16(gB + kc + (size_t)qq * 8 * DMODEL, lB + qq * 512);
        }
        __syncthreads();

        bf16x8 af[2][4], bfv[2][4];
#pragma unroll
        for (int ks = 0; ks < 2; ++ks)
#pragma unroll
            for (int i = 0; i < 4; ++i) {
                const int Ra = wm + i * 16 + ml;
                af[ks][i] = *(const bf16x8*)&As[Ra * 64 + (((ks * 4 + kq) ^ (Ra & 7)) << 3)];
                const int Rb = wn + i * 16 + ml;
                bfv[ks][i] = *(const bf16x8*)&Bs[Rb * 64 + (((ks * 4 + kq) ^ (Rb & 7)) << 3)];
            }
#pragma unroll
        for (int ks = 0; ks < 2; ++ks)
#pragma unroll
            for (int i = 0; i < 4; ++i)
#pragma unroll
                for (int j = 0; j < 4; ++j)
                    acc[i][j] = MFMA(af[ks][i], bfv[ks][j], acc[i][j]);
        __syncthreads();
    }

    if (z < 2) {
        unsigned short* dst = (z == 0) ? Qd : Kd;
        const float osc = (z == 0) ? QSCALE : 1.0f;
#pragma unroll
        for (int jt = 0; jt < 4; ++jt) {
            const int col = n0 + wn + jt * 16 + ml;
            const float bv = bias[col];
            const int nh = col >> 6, hh = col & 63;
            const int odd = hh & 1;
#pragma unroll
            for (int it = 0; it < 4; ++it) {
#pragma unroll
                for (int r = 0; r < 4; ++r) {
                    const int row = m0 + wm + it * 16 + kq * 4 + r;
                    const int bb = row >> 11, ll = row & 2047;
                    const float v = acc[it][jt][r] + bv;
                    const float partner = __shfl_xor(v, 1);
                    const float2 cs = ropetab[ll * 64 + hh];
                    const float res = odd ? fmaf(v, cs.x, partner * cs.y)
                                          : fmaf(v, cs.x, -partner * cs.y);
                    dst[(((size_t)(bb * NHEAD + nh) * L_SEQ + ll) << 6) + hh] = f2bf(res * osc);
                }
            }
        }
    } else {
#pragma unroll
        for (int jt = 0; jt < 4; ++jt) {
            const int col = n0 + wn + jt * 16 + ml;
            const float bv = bias[col];
            const int nh = col >> 6, hh = col & 63;
#pragma unroll
            for (int it = 0; it < 4; ++it) {
                const int rb = m0 + wm + it * 16 + kq * 4;
                const int bb = rb >> 11, ll = rb & 2047;
                uint2 pk;
                pk.x = pkbf(acc[it][jt][0] + bv, acc[it][jt][1] + bv);
                pk.y = pkbf(acc[it][jt][2] + bv, acc[it][jt][3] + bv);
                *(uint2*)&Vd[(((size_t)bb * NHEAD + nh) * HDIM + hh) * L_SEQ + ll] = pk;
            }
        }
    }
}

// ---------------------------------------------------------------------------
// Kernel B: flash attention, 32 q/wave (128 q/block, 512 blocks).
// LDS-staged dbuf global_load_lds, ONE barrier/tile; fixed-max log2 softmax.
// K-frags + mask nibbles shared across both q-subtiles -> K/V LDS reads
// amortized over 2x q (R8 was LDS-throughput-bound at 16 q/wave).
// LDS exactly 48 KB -> 3 blocks/CU.
// ---------------------------------------------------------------------------
__global__ __launch_bounds__(256) void attn_kernel(
    const unsigned short* __restrict__ Qr, const unsigned short* __restrict__ Kr,
    const unsigned short* __restrict__ Vt, const unsigned long long* __restrict__ mbits,
    unsigned short* __restrict__ AOhi, unsigned short* __restrict__ AOlo)
{
    __shared__ __align__(16) unsigned short Ks[2][64 * 64];  // 16 KB
    __shared__ __align__(16) unsigned short Vs[2][64 * 64];  // 16 KB
    __shared__ __align__(16) unsigned short Ps[4][32 * 64];  // 16 KB (per-wave)

    const int tid  = threadIdx.x;
    const int wave = tid >> 6, lane = tid & 63;
    const int ml = lane & 15, kq = lane >> 4;

    // 512 blocks: xcd-major, 4 bh per XCD.
    const int id = blockIdx.x;
    const int xcd = id & 7, slot = id >> 3;       // slot 0..63
    const int bh = xcd * 4 + (slot & 3);
    const int qb = slot >> 2;                     // 0..15
    const int b = bh >> 4, nh = bh & 15;
    const int q0 = qb * 128;
    const int wq = wave * 32;

    const unsigned short* Qp = Qr + (size_t)bh * L_SEQ * HDIM;
    const unsigned short* Kp = Kr + (size_t)bh * L_SEQ * HDIM;
    const unsigned short* Vp = Vt + (size_t)bh * HDIM * L_SEQ;

    // Q fragments: 32 q rows per wave (q = qt*16 + ml).
    bf16x8 qf[2][2];
#pragma unroll
    for (int qt = 0; qt < 2; ++qt)
#pragma unroll
        for (int c = 0; c < 2; ++c)
            qf[qt][c] = *(const bf16x8*)(Qp + (size_t)(q0 + wq + qt * 16 + ml) * HDIM + c * 32 + kq * 8);

    float li[2] = {0.f, 0.f};
    f32x4 o[2][4];
#pragma unroll
    for (int qt = 0; qt < 2; ++qt)
#pragma unroll
        for (int ht = 0; ht < 4; ++ht) o[qt][ht] = (f32x4){0.f, 0.f, 0.f, 0.f};

    unsigned short* Pw = Ps[wave];

    // Staging: wave stages rows [wave*16, +16) of K and V, 2 issues of 8 rows.
    const int srow8 = lane >> 3;
    const int sch   = (lane & 7) ^ srow8;
    const unsigned short* gK = Kp + (size_t)(wave * 16 + srow8) * HDIM + sch * 8;
    const unsigned short* gV = Vp + (size_t)(wave * 16 + srow8) * L_SEQ + sch * 8;

#define STAGE(kt, bf)                                                          \
    do {                                                                       \
        gl2lds16(gK + (size_t)((kt) * 64) * HDIM, &Ks[bf][(wave * 16) * 64]);  \
        gl2lds16(gK + (size_t)((kt) * 64 + 8) * HDIM,                          \
                 &Ks[bf][(wave * 16 + 8) * 64]);                               \
        gl2lds16(gV + (kt) * 64, &Vs[bf][(wave * 16) * 64]);                   \
        gl2lds16(gV + (size_t)8 * L_SEQ + (kt) * 64,                           \
                 &Vs[bf][(wave * 16 + 8) * 64]);                               \
    } while (0)

    STAGE(0, 0);

    for (int kt = 0; kt < L_SEQ / 64; ++kt) {
        const int buf = kt & 1;
        __syncthreads();                       // tile kt staged
        if (kt + 1 < L_SEQ / 64) STAGE(kt + 1, buf ^ 1);

        const unsigned short* Kb = Ks[buf];
        const unsigned short* Vb = Vs[buf];
        const unsigned long long mw = mbits[b * 32 + kt];

        // S^T = K·Q^T : K-frags read once, used for both q-subtiles.
        f32x4 st[2][4];
#pragma unroll
        for (int nt = 0; nt < 4; ++nt) {
            const int R = nt * 16 + ml;
            const bf16x8 kf0 = *(const bf16x8*)&Kb[R * 64 + ((kq ^ (R & 7)) << 3)];
            const bf16x8 kf1 = *(const bf16x8*)&Kb[R * 64 + (((4 + kq) ^ (R & 7)) << 3)];
#pragma unroll
            for (int qt = 0; qt < 2; ++qt) {
                f32x4 c = (f32x4){0.f, 0.f, 0.f, 0.f};
                c = MFMA(kf0, qf[qt][0], c);
                c = MFMA(kf1, qf[qt][1], c);
                st[qt][nt] = c;
            }
        }

        // Fixed-max softmax; P -> per-wave LDS (swizzled, unpadded).
        unsigned int nib[4];
#pragma unroll
        for (int nt = 0; nt < 4; ++nt)
            nib[nt] = ((unsigned int)(mw >> (nt * 16 + kq * 4))) & 0xFu;
#pragma unroll
        for (int qt = 0; qt < 2; ++qt) {
#pragma unroll
            for (int nt = 0; nt < 4; ++nt) {
                float p[4];
#pragma unroll
                for (int r = 0; r < 4; ++r) {
                    const float e = EXP2(st[qt][nt][r]);
                    p[r] = (nib[nt] & (1u << r)) ? 0.f : e;
                    li[qt] += p[r];
                }
                uint2 pk;
                pk.x = pkbf(p[0], p[1]);
                pk.y = pkbf(p[2], p[3]);
                const int row = qt * 16 + ml;
                const int ck = nt * 2 + (kq >> 1);
                *(uint2*)&Pw[row * 64 + ((ck ^ (ml & 7)) << 3) + (kq & 1) * 4] = pk;
            }
        }
        WAVE_FENCE();

        // O^T += V^T·P : V-frags read once, used for both q-subtiles.
        bf16x8 pf[2][2];
#pragma unroll
        for (int qt = 0; qt < 2; ++qt) {
            const int row = qt * 16 + ml;
            pf[qt][0] = *(const bf16x8*)&Pw[row * 64 + ((kq ^ (ml & 7)) << 3)];
            pf[qt][1] = *(const bf16x8*)&Pw[row * 64 + (((4 + kq) ^ (ml & 7)) << 3)];
        }
#pragma unroll
        for (int ht = 0; ht < 4; ++ht) {
            const int R = ht * 16 + ml;
            const bf16x8 vf0 = *(const bf16x8*)&Vb[R * 64 + ((kq ^ (R & 7)) << 3)];
            const bf16x8 vf1 = *(const bf16x8*)&Vb[R * 64 + (((4 + kq) ^ (R & 7)) << 3)];
#pragma unroll
            for (int qt = 0; qt < 2; ++qt) {
                o[qt][ht] = MFMA(vf0, pf[qt][0], o[qt][ht]);
                o[qt][ht] = MFMA(vf1, pf[qt][1], o[qt][ht]);
            }
        }
        WAVE_FENCE();  // Pw reads done before next tile overwrites
    }
#undef STAGE

    // li spans lanes ml, ml+16, ml+32, ml+48.
#pragma unroll
    for (int qt = 0; qt < 2; ++qt) {
        li[qt] += __shfl_xor(li[qt], 16);
        li[qt] += __shfl_xor(li[qt], 32);
    }
    const float inv[2] = {1.f / li[0], 1.f / li[1]};

    // Epilogue: O^T lane holds (h=ht*16+kq*4+r, q=qt*16+ml). Transpose via Pw.
    const int qr = lane >> 2, quarter = lane & 3;
    const int rc0 = (quarter * 2) ^ (qr & 7), rc1 = (quarter * 2 + 1) ^ (qr & 7);

    // hi plane: write all 32 rows, then 2 coalesced stores per qt.
#pragma unroll
    for (int qt = 0; qt < 2; ++qt)
#pragma unroll
        for (int ht = 0; ht < 4; ++ht) {
            uint2 pk;
            pk.x = pkbf(o[qt][ht][0] * inv[qt], o[qt][ht][1] * inv[qt]);
            pk.y = pkbf(o[qt][ht][2] * inv[qt], o[qt][ht][3] * inv[qt]);
            const int row = qt * 16 + ml;
            const int ck = ht * 2 + (kq >> 1);
            *(uint2*)&Pw[row * 64 + ((ck ^ (ml & 7)) << 3) + (kq & 1) * 4] = pk;
        }
    WAVE_FENCE();
#pragma unroll
    for (int qt = 0; qt < 2; ++qt) {
        const size_t gbase = ((size_t)b * L_SEQ + q0 + wq + qt * 16 + qr) * DMODEL
                             + nh * 64 + quarter * 16;
        const uint4 d0 = *(const uint4*)&Pw[(qt * 16 + qr) * 64 + (rc0 << 3)];
        const uint4 d1 = *(const uint4*)&Pw[(qt * 16 + qr) * 64 + (rc1 << 3)];
        *(uint4*)&AOhi[gbase]     = d0;
        *(uint4*)&AOhi[gbase + 8] = d1;
    }
    WAVE_FENCE();
    // lo plane
#pragma unroll
    for (int qt = 0; qt < 2; ++qt)
#pragma unroll
        for (int ht = 0; ht < 4; ++ht) {
            float lo[4];
#pragma unroll
            for (int r = 0; r < 4; ++r) {
                const float v = o[qt][ht][r] * inv[qt];
                const float hf = __uint_as_float((__float_as_uint(v) + 0x8000u) & 0xffff0000u);
                lo[r] = v - hf;
            }
            uint2 pk;
            pk.x = pkbf(lo[0], lo[1]);
            pk.y = pkbf(lo[2], lo[3]);
            const int row = qt * 16 + ml;
            const int ck = ht * 2 + (kq >> 1);
            *(uint2*)&Pw[row * 64 + ((ck ^ (ml & 7)) << 3) + (kq & 1) * 4] = pk;
        }
    WAVE_FENCE();
#pragma unroll
    for (int qt = 0; qt < 2; ++qt) {
        const size_t gbase = ((size_t)b * L_SEQ + q0 + wq + qt * 16 + qr) * DMODEL
                             + nh * 64 + quarter * 16;
        const uint4 d0 = *(const uint4*)&Pw[(qt * 16 + qr) * 64 + (rc0 << 3)];
        const uint4 d1 = *(const uint4*)&Pw[(qt * 16 + qr) * 64 + (rc1 << 3)];
        *(uint4*)&AOlo[gbase]     = d0;
        *(uint4*)&AOlo[gbase + 8] = d1;
    }
}

// ---------------------------------------------------------------------------
// Kernel C: out = AO @ Wo^T + bo, 3-term bf16-split. 128x64 tiles, 512
// blocks = 2 blocks/CU (R8's 256-block config was 1 block/CU: barrier-
// serialized, latency-starved). id%8 == by%8 -> A-panel XCD colocation.
// ---------------------------------------------------------------------------
__global__ __launch_bounds__(256) void oproj_kernel(
    const unsigned short* __restrict__ Ahi_g, const unsigned short* __restrict__ Alo_g,
    const unsigned short* __restrict__ Whi_g, const unsigned short* __restrict__ Wlo_g,
    const float* __restrict__ bias, float* __restrict__ out)
{
    const int id = blockIdx.x;
    const int bxn = id >> 5, by = id & 31;

    __shared__ __align__(16) unsigned short Ah[128 * 32], Al[128 * 32];  // 8 KB ea
    __shared__ __align__(16) unsigned short Bh[64 * 32],  Bl[64 * 32];   // 4 KB ea

    const int tid  = threadIdx.x;
    const int wave = tid >> 6, lane = tid & 63;
    const int ml = lane & 15, kq = lane >> 4;
    const int m0 = by * 128, n0 = bxn * 64;
    const int wm = (wave & 1) * 64, wn = (wave >> 1) * 32;

    f32x4 acc[4][2];
#pragma unroll
    for (int i = 0; i < 4; ++i)
#pragma unroll
        for (int j = 0; j < 2; ++j) acc[i][j] = (f32x4){0.f, 0.f, 0.f, 0.f};

    const int rl  = lane >> 2;                       // 0..15 rows per issue
    const int pch = (lane & 3) ^ ((lane >> 3) & 3);
    const int prowA = wave * 32 + rl;
    const int prowB = wave * 16 + rl;
    const unsigned short* gAh = Ahi_g + (size_t)(m0 + prowA) * DMODEL + pch * 8;
    const unsigned short* gAl = Alo_g + (size_t)(m0 + prowA) * DMODEL + pch * 8;
    const unsigned short* gBh = Whi_g + (size_t)(n0 + prowB) * DMODEL + pch * 8;
    const unsigned short* gBl = Wlo_g + (size_t)(n0 + prowB) * DMODEL + pch * 8;
    unsigned short* lAh = Ah + wave * 1024;
    unsigned short* lAl = Al + wave * 1024;
    unsigned short* lBh = Bh + wave * 512;
    unsigned short* lBl = Bl + wave * 512;

    for (int kc = 0; kc < DMODEL; kc += 32) {
#pragma unroll
        for (int qq = 0; qq < 2; ++qq) {
            const size_t go = kc + (size_t)qq * 16 * DMODEL;
            gl2lds16(gAh + go, lAh + qq * 512);
            gl2lds16(gAl + go, lAl + qq * 512);
        }
        gl2lds16(gBh + kc, lBh);
        gl2lds16(gBl + kc, lBl);
        __syncthreads();

        bf16x8 ah[4], al[4], bh_[2], bl_[2];
#pragma unroll
        for (int i = 0; i < 4; ++i) {
            const int Ra = wm + i * 16 + ml;
            const int sa = Ra * 32 + ((kq ^ ((Ra >> 1) & 3)) << 3);
            ah[i] = *(const bf16x8*)&Ah[sa];
            al[i] = *(const bf16x8*)&Al[sa];
        }
#pragma unroll
        for (int j = 0; j < 2; ++j) {
            const int Rb = wn + j * 16 + ml;
            const int sb = Rb * 32 + ((kq ^ ((Rb >> 1) & 3)) << 3);
            bh_[j] = *(const bf16x8*)&Bh[sb];
            bl_[j] = *(const bf16x8*)&Bl[sb];
        }
#pragma unroll
        for (int i = 0; i < 4; ++i)
#pragma unroll
            for (int j = 0; j < 2; ++j) {
                acc[i][j] = MFMA(ah[i], bh_[j], acc[i][j]);
                acc[i][j] = MFMA(al[i], bh_[j], acc[i][j]);
                acc[i][j] = MFMA(ah[i], bl_[j], acc[i][j]);
            }
        __syncthreads();
    }

#pragma unroll
    for (int jt = 0; jt < 2; ++jt) {
        const int col = n0 + wn + jt * 16 + ml;
        const float bv = bias[col];
#pragma unroll
        for (int it = 0; it < 4; ++it)
#pragma unroll
            for (int r = 0; r < 4; ++r) {
                const int row = m0 + wm + it * 16 + kq * 4 + r;
                out[(size_t)row * DMODEL + col] = acc[it][jt][r] + bv;
            }
    }
}

extern "C" void kernel_launch(void* const* d_in, const int* in_sizes, int n_in,
                              void* d_out, int out_size, void* d_ws, size_t ws_size,
                              hipStream_t stream)
{
    (void)in_sizes; (void)n_in; (void)out_size; (void)ws_size;
    const float* q    = (const float*)d_in[0];
    const float* k    = (const float*)d_in[1];
    const float* v    = (const float*)d_in[2];
    const int*   mask = (const int*)d_in[3];
    const float* Wq   = (const float*)d_in[4];
    const float* bq   = (const float*)d_in[5];
    const float* Wk   = (const float*)d_in[6];
    const float* bk   = (const float*)d_in[7];
    const float* Wv   = (const float*)d_in[8];
    const float* bv   = (const float*)d_in[9];
    const float* Wo   = (const float*)d_in[10];
    const float* bo   = (const float*)d_in[11];
    float* out = (float*)d_out;

    const size_t HE = (size_t)BATCH * NHEAD * L_SEQ * HDIM;   // 4,194,304
    const size_t DD = (size_t)DMODEL * DMODEL;                // 1,048,576
    unsigned short* Xb   = (unsigned short*)d_ws;             // 24 MB
    unsigned short* Wb   = Xb + 3 * HE;                       // 6 MB
    unsigned short* Qr   = Wb + 3 * DD;
    unsigned short* Kr   = Qr + HE;
    unsigned short* Vt   = Kr + HE;
    unsigned short* Whi  = Vt + HE;
    unsigned short* Wlo  = Whi + DD;
    unsigned long long* mbits = (unsigned long long*)(Wlo + DD);
    float2* ropetab = (float2*)(mbits + BATCH * L_SEQ / 64);
    unsigned short* AOhi = Xb;          // alias Xb (qkv done reading)
    unsigned short* AOlo = Xb + HE;

    prep_kernel<<<dim3(2048, 8), dim3(256), 0, stream>>>(
        q, k, v, Wq, Wk, Wv, Wo, mask, Xb, Wb, Whi, Wlo, ropetab, mbits);

    qkv_kernel<<<dim3(768), dim3(256), 0, stream>>>(Xb, Wb, bq, bk, bv, ropetab, Qr, Kr, Vt);

    attn_kernel<<<dim3(512), dim3(256), 0, stream>>>(Qr, Kr, Vt, mbits, AOhi, AOlo);

    oproj_kernel<<<dim3(512), dim3(256), 0, stream>>>(AOhi, AOlo, Whi, Wlo, bo, out);
}